// Round 5
// baseline (418.095 us; speedup 1.0000x reference)
//
#include <hip/hip_runtime.h>
#include <stdint.h>

#define IC      4096
#define BLK     256
#define RPB     4          // rows per block = waves per block (one row per wave)
#define CHUNKS  16         // float4 chunks per lane
#define EPT     64         // elements per lane (64 lanes x 64 = 4096 = one row)

__global__ __launch_bounds__(BLK) void binarize_kernel(
    const float* __restrict__ x,
    const uint8_t* __restrict__ mask,
    float* __restrict__ out,
    int nrows)
{
    const int lane = threadIdx.x & 63;
    const int row  = blockIdx.x * RPB + (threadIdx.x >> 6);
    if (row >= nrows) return;

    // ---- mask dtype detection (wave-uniform, no LDS/barrier) ----
    // int32 0/1 mask: every 32-bit word <= 1. byte bool mask: P(first 64
    // words all <= 1) = (1/8)^64 ~ 0.
    const bool mask_is_i32 = !__any(((const uint32_t*)mask)[lane] > 1u);

    const float* xr   = x   + (size_t)row * IC;
    float*       orow = out + (size_t)row * IC;

    // ---- load x row: 16 fully-coalesced float4 per lane ----
    float xm[EPT];
    #pragma unroll
    for (int i = 0; i < CHUNKS; ++i) {
        float4 v = ((const float4*)xr)[lane + 64 * i];
        xm[4*i+0] = v.x; xm[4*i+1] = v.y; xm[4*i+2] = v.z; xm[4*i+3] = v.w;
    }

    // ---- load mask -> 64-bit per-lane bitmask (2x u32, compile-time indexed) ----
    uint32_t mw0 = 0, mw1 = 0;
    if (mask_is_i32) {
        const int4* mr = (const int4*)mask + (size_t)row * (IC / 4);
        #pragma unroll
        for (int i = 0; i < CHUNKS; ++i) {
            int4 m4 = mr[lane + 64 * i];
            uint32_t b = (uint32_t)(m4.x != 0)
                       | ((uint32_t)(m4.y != 0) << 1)
                       | ((uint32_t)(m4.z != 0) << 2)
                       | ((uint32_t)(m4.w != 0) << 3);
            if (i < 8) mw0 |= b << (4 * i);
            else       mw1 |= b << (4 * (i - 8));
        }
    } else {
        const uint32_t* mr = (const uint32_t*)(mask + (size_t)row * IC);
        #pragma unroll
        for (int i = 0; i < CHUNKS; ++i) {
            uint32_t w = mr[lane + 64 * i];
            uint32_t b = (uint32_t)((w & 0x000000ffu) != 0)
                       | ((uint32_t)((w & 0x0000ff00u) != 0) << 1)
                       | ((uint32_t)((w & 0x00ff0000u) != 0) << 2)
                       | ((uint32_t)((w & 0xff000000u) != 0) << 3);
            if (i < 8) mw0 |= b << (4 * i);
            else       mw1 |= b << (4 * (i - 8));
        }
    }

    #pragma unroll
    for (int j = 0; j < EPT; ++j) {
        const uint32_t bit = ((j < 32 ? mw0 : mw1) >> (j & 31)) & 1u;
        xm[j] = bit ? xm[j] : 0.f;          // exact masking
    }

    // ---- pass A: s = sum(x*m) [f64, dual accum], c = popcount (exact) ----
    double sA0 = 0.0, sA1 = 0.0;
    #pragma unroll
    for (int j = 0; j < EPT; j += 2) {
        sA0 += (double)xm[j];
        sA1 += (double)xm[j + 1];
    }
    double s  = sA0 + sA1;
    float  cf = (float)(__popc(mw0) + __popc(mw1));
    #pragma unroll
    for (int off = 32; off; off >>= 1) {      // wave butterfly, no barrier
        s  += __shfl_xor(s,  off);
        cf += __shfl_xor(cf, off);
    }

    const bool   has    = (cf > 0.f);
    const double c      = (double)cf;
    const double nmiss  = (double)(4096.f - cf);   // # unmasked, exact
    const double inv    = 1.0 / fmax(c, 1.0);
    const double mean1  = has ? s * inv : 0.0;
    const float  mean1f = (float)mean1;

    // ---- pass B (f32 element math, f64 accumulate):
    // sum|x*m - mean1f| over ALL lanes; unmasked elements contribute exactly
    // |mean1f| -> corrected after reduction. Sign from f32 sub (Sterbenz-
    // exact near the boundary). d = sum sign1*m (f32 exact). ----
    double saB0 = 0.0, saB1 = 0.0;
    float  dB0 = 0.f, dB1 = 0.f;
    #pragma unroll
    for (int j = 0; j < EPT; ++j) {
        const uint32_t bit = ((j < 32 ? mw0 : mw1) >> (j & 31)) & 1u;
        const float t   = xm[j] - mean1f;
        const float sg  = (t > 0.f) ? 1.f : ((t < 0.f) ? -1.f : 0.f);
        const float smv = bit ? sg : 0.f;
        if (j & 1) { dB1 += smv; saB1 += (double)fabsf(t); }
        else       { dB0 += smv; saB0 += (double)fabsf(t); }
    }
    double sa = saB0 + saB1;
    float  df = dB0 + dB1;
    #pragma unroll
    for (int off = 32; off; off >>= 1) {
        sa += __shfl_xor(sa, off);
        df += __shfl_xor(df, off);
    }
    sa -= nmiss * (double)fabsf(mean1f);      // remove unmasked contributions

    const double scale1 = has ? sa * inv : 0.0;
    // pass C eliminated: sum((x-b1)*m) = s - scale1*d - mean1*c  (b1 = sign1*scale1 + mean1)
    const double mean2  = has ? (s - scale1 * (double)df - mean1 * c) * inv : 0.0;
    const double mean12 = mean1 + mean2;

    // ---- pass D (f64 element math): scale2 = mean |x - b1 - mean2| over mask.
    // sign1 recomputed (identical ops -> identical values, no sgm[] cache).
    // Unmasked: smv==0 -> t2 == -mean12 exactly -> corrected after. ----
    double sb0 = 0.0, sb1 = 0.0;
    #pragma unroll
    for (int j = 0; j < EPT; ++j) {
        const uint32_t bit = ((j < 32 ? mw0 : mw1) >> (j & 31)) & 1u;
        const float t   = xm[j] - mean1f;
        const float sg  = (t > 0.f) ? 1.f : ((t < 0.f) ? -1.f : 0.f);
        const float smv = bit ? sg : 0.f;
        const double t2 = (double)xm[j] - fma((double)smv, scale1, mean12);
        if (j & 1) sb1 += fabs(t2); else sb0 += fabs(t2);
    }
    double sa2 = sb0 + sb1;
    #pragma unroll
    for (int off = 32; off; off >>= 1) sa2 += __shfl_xor(sa2, off);
    sa2 -= nmiss * fabs(mean12);
    const double scale2  = has ? sa2 * inv : 0.0;
    const float  scale2f = (float)scale2;

    // ---- epilogue (f32): out = (b1 + sign2*scale2 + mean2) * m
    // t2 recomputed identically; b1 + mean2 == x - t2; sign2 from (float)t2
    // (sign-exact). Same numerics class as the verified round-4 kernel. ----
    #pragma unroll
    for (int i = 0; i < CHUNKS; ++i) {
        float r[4];
        #pragma unroll
        for (int k = 0; k < 4; ++k) {
            const int j = 4 * i + k;
            const uint32_t bit = ((j < 32 ? mw0 : mw1) >> (j & 31)) & 1u;
            const float t   = xm[j] - mean1f;
            const float sg  = (t > 0.f) ? 1.f : ((t < 0.f) ? -1.f : 0.f);
            const float smv = bit ? sg : 0.f;
            const double t2 = (double)xm[j] - fma((double)smv, scale1, mean12);
            const float t2f = (float)t2;
            const float b1f = xm[j] - t2f;               // b1 + mean2
            const float sg2 = (t2f > 0.f) ? 1.f : ((t2f < 0.f) ? -1.f : 0.f);
            const float o   = fmaf(sg2, scale2f, b1f);
            r[k] = bit ? o : 0.f;                        // unmasked -> exact 0
        }
        float4 o4; o4.x = r[0]; o4.y = r[1]; o4.z = r[2]; o4.w = r[3];
        ((float4*)orow)[lane + 64 * i] = o4;
    }
}

extern "C" void kernel_launch(void* const* d_in, const int* in_sizes, int n_in,
                              void* d_out, int out_size, void* d_ws, size_t ws_size,
                              hipStream_t stream) {
    const float*   x    = (const float*)d_in[0];
    const uint8_t* mask = (const uint8_t*)d_in[1];
    float*         out  = (float*)d_out;

    const int rows = in_sizes[0] / IC;        // 11008
    const int grid = (rows + RPB - 1) / RPB;  // 2752
    binarize_kernel<<<grid, BLK, 0, stream>>>(x, mask, out, rows);
}